// Round 2
// baseline (461.762 us; speedup 1.0000x reference)
//
#include <hip/hip_runtime.h>
#include <hip/hip_bf16.h>

#define N_ 64
#define C_ 256
#define T_ 64
#define V_ 25
#define K_ 8
#define VN_ 5
#define VT_ 30
#define CG_ 32
#define H_ 8
#define O_ 256
#define OG_ 32
#define TOPK_ 9

// ---------------- Kernel 1: T-mean pooling + hyper fill + output-tail copy ----
__global__ __launch_bounds__(256) void k_pool(const float* __restrict__ x,
                                              const float* __restrict__ hyper,
                                              float* __restrict__ pooled,
                                              float* __restrict__ out_tail) {
    int idx = blockIdx.x * 256 + threadIdx.x;
    const int A = N_ * C_ * V_;
    const int B = N_ * C_ * VN_;
    if (idx < A) {
        int u = idx % V_;
        int c = (idx / V_) % C_;
        int n = idx / (V_ * C_);
        const float* p = x + ((size_t)(n * C_ + c) * T_) * V_ + u;
        float s = 0.f;
        #pragma unroll 4
        for (int t = 0; t < T_; ++t) s += p[t * V_];
        pooled[(n * C_ + c) * VT_ + u] = s * (1.0f / T_);
    } else if (idx < A + B) {
        int r = idx - A;
        int j = r % VN_;
        int c = (r / VN_) % C_;
        int n = r / (VN_ * C_);
        pooled[(n * C_ + c) * VT_ + V_ + j] = hyper[j * C_ + c];
    } else if (idx < A + B + VN_ * C_) {
        int r = idx - A - B;
        out_tail[r] = hyper[r];   // second output: hyper_joint passthrough
    }
}

// ---------------- Kernel 2: per-sample graph construction -> adj_full --------
// LDS phase-aliased: 48000 B total.
__global__ __launch_bounds__(256) void k_graph(
    const float* __restrict__ pooled,
    const float* __restrict__ adjc, const float* __restrict__ edge,
    const float* __restrict__ alpha,
    const float* __restrict__ to_v_w, const float* __restrict__ to_v_b,
    const float* __restrict__ to_w1_w, const float* __restrict__ to_w1_b,
    const float* __restrict__ to_w2_w, const float* __restrict__ to_w2_b,
    float* __restrict__ adj_full) {
    __shared__ float smem[12000];
    float* vproj = smem;              // 1920: [k][v][h]
    float* w1s   = smem + 1920;       // 1920: [q][v], q=k*H+h
    float* pg    = smem + 3840;       // 7680: [c][v]  (phase A only)
    float* inc   = smem + 3840;       // 7200: [k][u][v] (phase B, aliases pg)
    float* wt    = smem + 11040;      // 240
    float* gv    = smem + 11280;      // 240
    float* rs    = smem + 11520;      // 240
    float* rsA   = smem + 11760;      // 240

    int n = blockIdx.x;
    int tid = threadIdx.x;
    for (int i = tid; i < C_ * VT_; i += 256) pg[i] = pooled[n * C_ * VT_ + i];
    __syncthreads();

    // vproj[k][v][h] and leaky_relu(w1)[q][v]  (read pg)
    for (int i = tid; i < K_ * VT_ * H_; i += 256) {
        int k = i / (VT_ * H_);
        int r = i % (VT_ * H_);
        int v = r / H_, h = r % H_;
        const float* w = to_v_w + (k * H_ + h) * CG_;
        const float* pgk = pg + (k * CG_) * VT_ + v;
        float s = 0.f;
        #pragma unroll
        for (int c = 0; c < CG_; ++c) s += pgk[c * VT_] * w[c];
        vproj[(k * VT_ + v) * H_ + h] = s + to_v_b[k * H_ + h];
    }
    for (int i = tid; i < K_ * H_ * VT_; i += 256) {
        int k = i / (H_ * VT_);
        int r = i % (H_ * VT_);
        int h = r / VT_, v = r % VT_;
        const float* w = to_w1_w + (k * H_ + h) * CG_;
        const float* pgk = pg + (k * CG_) * VT_ + v;
        float s = 0.f;
        #pragma unroll
        for (int c = 0; c < CG_; ++c) s += pgk[c * VT_] * w[c];
        s += to_w1_b[k * H_ + h];
        w1s[(k * H_ + h) * VT_ + v] = (s > 0.f) ? s : 0.01f * s;  // leaky_relu
    }
    __syncthreads();   // pg dead after this barrier

    // weights (tanh over q=K*H), adjacency row norms, incidence rows
    if (tid < K_ * VT_) {
        int k = tid / VT_;
        float s = to_w2_b[k];
        #pragma unroll
        for (int q = 0; q < K_ * H_; ++q)
            s += w1s[q * VT_ + (tid % VT_)] * to_w2_w[k * K_ * H_ + q];
        wt[tid] = tanhf(s);
        // adjacency row norm for row (k,u) over last axis
        float sa = 0.f;
        const float* ea = edge + (size_t)tid * VT_;
        const float* aa = adjc + (size_t)tid * VT_;
        #pragma unroll
        for (int w2 = 0; w2 < VT_; ++w2) sa += fabsf(ea[w2] * aa[w2]);
        rsA[tid] = sa + 1e-8f;
    }
    if (tid < K_ * VT_) {
        int k = tid / VT_, u = tid % VT_;
        const float* vu = vproj + (k * VT_ + u) * H_;
        float nd[VT_];
        #pragma unroll
        for (int v = 0; v < VT_; ++v) {
            const float* vv = vproj + (k * VT_ + v) * H_;
            float d2 = 0.f;
            #pragma unroll
            for (int h = 0; h < H_; ++h) { float df = vu[h] - vv[h]; d2 += df * df; }
            nd[v] = (d2 > 0.f) ? -sqrtf(d2) : 0.0f;   // -dist
        }
        unsigned taken = 0;
        float vals[TOPK_]; int ids[TOPK_];
        for (int j = 0; j < TOPK_; ++j) {
            float best = -3.4e38f; int bi = 0;
            #pragma unroll
            for (int v = 0; v < VT_; ++v) {
                if (!((taken >> v) & 1u) && nd[v] > best) { best = nd[v]; bi = v; }
            }
            vals[j] = best; ids[j] = bi; taken |= (1u << bi);
        }
        float m = vals[0], se = 0.f, e[TOPK_];
        #pragma unroll
        for (int j = 0; j < TOPK_; ++j) { e[j] = expf(vals[j] - m); se += e[j]; }
        float invse = 1.f / se;
        float* row = inc + (size_t)tid * VT_;
        #pragma unroll
        for (int v = 0; v < VT_; ++v) row[v] = 0.f;
        for (int j = 0; j < TOPK_; ++j) row[ids[j]] = e[j] * invse;
    }
    __syncthreads();

    // column sums -> d -> gv ; row sums of |inc*wt| -> rs
    if (tid < K_ * VT_) {
        int k = tid / VT_, v = tid % VT_;
        float cs = 0.f;
        #pragma unroll
        for (int u = 0; u < VT_; ++u) cs += fabsf(inc[(k * VT_ + u) * VT_ + v]);
        float d = wt[tid] / (cs + 1e-8f);
        gv[tid] = wt[tid] * d;
        float s = 0.f;
        const float* row = inc + (size_t)tid * VT_;
        const float* w = wt + k * VT_;
        #pragma unroll
        for (int vv = 0; vv < VT_; ++vv) s += fabsf(row[vv] * w[vv]);
        rs[tid] = s + 1e-8f;
    }
    __syncthreads();

    // adj_full = adj_norm + relu(alpha) * hyper_adj
    float ar = alpha[0]; ar = ar > 0.f ? ar : 0.f;
    for (int i = tid; i < K_ * VT_ * VT_; i += 256) {
        int k = i / (VT_ * VT_);
        int r = i % (VT_ * VT_);
        int u = r / VT_;
        const float* ru = inc + (k * VT_ + u) * VT_;
        const float* rw = inc + (k * VT_ + (r % VT_)) * VT_;
        const float* g = gv + k * VT_;
        float s = 0.f;
        #pragma unroll
        for (int v = 0; v < VT_; ++v) s += ru[v] * g[v] * rw[v];
        float ha = s / rs[k * VT_ + u];
        float an = edge[i] * adjc[i] / rsA[k * VT_ + u];
        adj_full[(size_t)n * K_ * VT_ * VT_ + i] = an + ar * ha;
    }
}

// ---------------- Kernel 3: dense conv + adj contraction + bn/residual/relu --
__global__ __launch_bounds__(256) void k_main(
    const float* __restrict__ x, const float* __restrict__ hyper,
    const float* __restrict__ adj_full,
    const float* __restrict__ conv_w, const float* __restrict__ conv_b,
    const float* __restrict__ gamma, const float* __restrict__ beta,
    float* __restrict__ out) {
    __shared__ float Wsh[OG_ * 33];     // conv_d_w[k], stride 33 (conflict-free)
    __shared__ float AshT[VT_ * 28];    // adj_full[u<25][v] -> [v][u], pad 28
    __shared__ float xvs[CG_ * 32];     // xv tile [c][v], stride 32 (float4-aligned)
    __shared__ float dens[OG_ * 33];    // den [o][v], stride 33
    __shared__ float sc[OG_], bt[OG_], bb[OG_];

    int nk = blockIdx.x;
    int n = nk / K_, k = nk % K_;
    int tid = threadIdx.x;

    for (int i = tid; i < OG_ * CG_; i += 256) {
        int o = i / CG_, c = i % CG_;
        Wsh[o * 33 + c] = conv_w[(k * OG_ + o) * CG_ + c];
    }
    for (int i = tid; i < VT_ * 28; i += 256) {
        int v = i / 28, u = i % 28;
        AshT[i] = (u < V_) ? adj_full[(((size_t)n * K_ + k) * VT_ + u) * VT_ + v] : 0.f;
    }
    if (tid < OG_) {
        sc[tid] = gamma[k * OG_ + tid] * 0.999995000037f;  // 1/sqrt(1+1e-5)
        bt[tid] = beta[k * OG_ + tid];
        bb[tid] = conv_b[k * OG_ + tid];
        xvs[tid * 32 + 30] = 0.f; xvs[tid * 32 + 31] = 0.f;  // v-pad, stays 0
    }
    __syncthreads();

    const int o_d = tid >> 3, g_d = tid & 7;         // den stage: (o, v-quad)
    const int o_y = tid / 7, g_y = tid % 7;          // y stage (tid<224): (o, u-quad)

    for (int t = 0; t < T_; ++t) {
        for (int i = tid; i < CG_ * VT_; i += 256) {
            int c = i / VT_, v = i % VT_;
            float val;
            if (v < V_) val = x[((size_t)(n * C_ + k * CG_ + c) * T_ + t) * V_ + v];
            else        val = hyper[(v - V_) * C_ + k * CG_ + c];
            xvs[c * 32 + v] = val;
        }
        __syncthreads();

        {   // den[o][4g..4g+3] = b[o] + sum_c W[o][c] * xv[c][v]
            float a0 = bb[o_d], a1 = a0, a2 = a0, a3 = a0;
            const float* wrow = Wsh + o_d * 33;
            const float4* xcol = (const float4*)(xvs) + g_d;   // + c*8 each step
            #pragma unroll
            for (int c = 0; c < CG_; ++c) {
                float w = wrow[c];
                float4 xq = xcol[c * 8];
                a0 += w * xq.x; a1 += w * xq.y; a2 += w * xq.z; a3 += w * xq.w;
            }
            float* dptr = dens + o_d * 33 + 4 * g_d;
            dptr[0] = a0; dptr[1] = a1; dptr[2] = a2; dptr[3] = a3;
        }
        __syncthreads();

        if (tid < 224) {   // y[o][4g..4g+3] = sum_v den[o][v] * A[u][v]; epilogue
            float a0 = 0.f, a1 = 0.f, a2 = 0.f, a3 = 0.f;
            const float* drow = dens + o_y * 33;
            const float4* acol = (const float4*)(AshT) + g_y;  // + v*7 each step
            #pragma unroll
            for (int v = 0; v < VT_; ++v) {
                float dv = drow[v];
                float4 a4 = acol[v * 7];
                a0 += dv * a4.x; a1 += dv * a4.y; a2 += dv * a4.z; a3 += dv * a4.w;
            }
            size_t base = ((size_t)(n * O_ + k * OG_ + o_y) * T_ + t) * V_;
            float s = sc[o_y], b = bt[o_y];
            float r[4] = {a0, a1, a2, a3};
            #pragma unroll
            for (int j = 0; j < 4; ++j) {
                int u = 4 * g_y + j;
                if (u < V_) {
                    float val = r[j] * s + b + xvs[o_y * 32 + u];  // + residual x
                    val = val > 0.f ? val : 0.f;                   // relu
                    out[base + u] = val;
                }
            }
        }
        __syncthreads();
    }
}

extern "C" void kernel_launch(void* const* d_in, const int* in_sizes, int n_in,
                              void* d_out, int out_size, void* d_ws, size_t ws_size,
                              hipStream_t stream) {
    const float* x     = (const float*)d_in[0];
    const float* adjc  = (const float*)d_in[1];
    const float* edge  = (const float*)d_in[2];
    const float* hyper = (const float*)d_in[3];
    const float* alpha = (const float*)d_in[4];
    const float* tvw   = (const float*)d_in[5];
    const float* tvb   = (const float*)d_in[6];
    const float* t1w   = (const float*)d_in[7];
    const float* t1b   = (const float*)d_in[8];
    const float* t2w   = (const float*)d_in[9];
    const float* t2b   = (const float*)d_in[10];
    const float* cw    = (const float*)d_in[11];
    const float* cb    = (const float*)d_in[12];
    const float* gam   = (const float*)d_in[13];
    const float* bet   = (const float*)d_in[14];
    float* out = (float*)d_out;

    float* pooled   = (float*)d_ws;                   // N*C*VT fp32
    float* adj_full = pooled + N_ * C_ * VT_;         // N*K*VT*VT fp32

    int total1 = N_ * C_ * V_ + N_ * C_ * VN_ + VN_ * C_;
    k_pool<<<dim3((total1 + 255) / 256), dim3(256), 0, stream>>>(
        x, hyper, pooled, out + (size_t)N_ * O_ * T_ * V_);
    k_graph<<<dim3(N_), dim3(256), 0, stream>>>(
        pooled, adjc, edge, alpha, tvw, tvb, t1w, t1b, t2w, t2b, adj_full);
    k_main<<<dim3(N_ * K_), dim3(256), 0, stream>>>(
        x, hyper, adj_full, cw, cb, gam, bet, out);
}

// Round 3
// 389.003 us; speedup vs baseline: 1.1870x; 1.1870x over previous
//
#include <hip/hip_runtime.h>
#include <hip/hip_bf16.h>

#define N_ 64
#define C_ 256
#define T_ 64
#define V_ 25
#define K_ 8
#define VN_ 5
#define VT_ 30
#define CG_ 32
#define H_ 8
#define O_ 256
#define OG_ 32
#define TOPK_ 9

// ---------------- Kernel 1: coalesced T-mean pooling (+ output-tail copy) ----
// Block b < 4096: (n, c0=4c-chunk). Loads 4*1600 floats contiguously, reduces.
// Block 4096: copies hyper_joint to out tail.
__global__ __launch_bounds__(256) void k_pool(const float* __restrict__ x,
                                              const float* __restrict__ hyper,
                                              float* __restrict__ pooled,
                                              float* __restrict__ out_tail) {
    __shared__ float ls[6400];
    int b = blockIdx.x;
    int tid = threadIdx.x;
    if (b >= N_ * 64) {   // tail block: hyper passthrough (VN_*C_ = 1280)
        for (int i = tid; i < VN_ * C_; i += 256) out_tail[i] = hyper[i];
        return;
    }
    int n = b >> 6, c0 = (b & 63) * 4;
    const float4* xp = (const float4*)(x + (size_t)(n * C_ + c0) * (T_ * V_));
    for (int i = tid; i < 1600; i += 256) ((float4*)ls)[i] = xp[i];
    __syncthreads();
    if (tid < 100) {
        int c_l = tid / 25, v = tid % 25;
        const float* p = ls + c_l * 1600 + v;
        float s = 0.f;
        #pragma unroll
        for (int t = 0; t < T_; ++t) s += p[t * 25];
        pooled[(size_t)(n * C_ + c0 + c_l) * 25 + v] = s * (1.0f / T_);
    }
}

// ---------------- Kernel 2: per-sample graph construction -> ATg -------------
// ATg[n][k][v][u], stride 32 in u, cols u=30,31 zeroed (k_main reads float4s).
__global__ __launch_bounds__(256) void k_graph(
    const float* __restrict__ pooled, const float* __restrict__ hyper,
    const float* __restrict__ adjc, const float* __restrict__ edge,
    const float* __restrict__ alpha,
    const float* __restrict__ to_v_w, const float* __restrict__ to_v_b,
    const float* __restrict__ to_w1_w, const float* __restrict__ to_w1_b,
    const float* __restrict__ to_w2_w, const float* __restrict__ to_w2_b,
    float* __restrict__ ATg) {
    __shared__ float smem[12000];
    float* vproj = smem;              // 1920: [k][v][h]
    float* w1s   = smem + 1920;       // 1920: [q][v], q=k*H+h
    float* pg    = smem + 3840;       // 7680: [c][v]  (phase A only)
    float* inc   = smem + 3840;       // 7200: [k][u][v] (phase B, aliases pg)
    float* wt    = smem + 11040;      // 240
    float* gv    = smem + 11280;      // 240
    float* rs    = smem + 11520;      // 240
    float* rsA   = smem + 11760;      // 240

    int n = blockIdx.x;
    int tid = threadIdx.x;
    for (int i = tid; i < C_ * V_; i += 256) {
        int c = i / V_, v = i % V_;
        pg[c * VT_ + v] = pooled[(size_t)n * C_ * V_ + i];
    }
    for (int i = tid; i < C_ * VN_; i += 256) {
        int c = i / VN_, j = i % VN_;
        pg[c * VT_ + V_ + j] = hyper[j * C_ + c];
    }
    __syncthreads();

    for (int i = tid; i < K_ * VT_ * H_; i += 256) {
        int k = i / (VT_ * H_);
        int r = i % (VT_ * H_);
        int v = r / H_, h = r % H_;
        const float* w = to_v_w + (k * H_ + h) * CG_;
        const float* pgk = pg + (k * CG_) * VT_ + v;
        float s = 0.f;
        #pragma unroll
        for (int c = 0; c < CG_; ++c) s += pgk[c * VT_] * w[c];
        vproj[(k * VT_ + v) * H_ + h] = s + to_v_b[k * H_ + h];
    }
    for (int i = tid; i < K_ * H_ * VT_; i += 256) {
        int k = i / (H_ * VT_);
        int r = i % (H_ * VT_);
        int h = r / VT_, v = r % VT_;
        const float* w = to_w1_w + (k * H_ + h) * CG_;
        const float* pgk = pg + (k * CG_) * VT_ + v;
        float s = 0.f;
        #pragma unroll
        for (int c = 0; c < CG_; ++c) s += pgk[c * VT_] * w[c];
        s += to_w1_b[k * H_ + h];
        w1s[(k * H_ + h) * VT_ + v] = (s > 0.f) ? s : 0.01f * s;  // leaky_relu
    }
    __syncthreads();   // pg dead after this barrier

    if (tid < K_ * VT_) {
        int k = tid / VT_;
        float s = to_w2_b[k];
        #pragma unroll
        for (int q = 0; q < K_ * H_; ++q)
            s += w1s[q * VT_ + (tid % VT_)] * to_w2_w[k * K_ * H_ + q];
        wt[tid] = tanhf(s);
        float sa = 0.f;
        const float* ea = edge + (size_t)tid * VT_;
        const float* aa = adjc + (size_t)tid * VT_;
        #pragma unroll
        for (int w2 = 0; w2 < VT_; ++w2) sa += fabsf(ea[w2] * aa[w2]);
        rsA[tid] = sa + 1e-8f;
    }
    if (tid < K_ * VT_) {
        int k = tid / VT_, u = tid % VT_;
        const float* vu = vproj + (k * VT_ + u) * H_;
        float nd[VT_];
        #pragma unroll
        for (int v = 0; v < VT_; ++v) {
            const float* vv = vproj + (k * VT_ + v) * H_;
            float d2 = 0.f;
            #pragma unroll
            for (int h = 0; h < H_; ++h) { float df = vu[h] - vv[h]; d2 += df * df; }
            nd[v] = (d2 > 0.f) ? -sqrtf(d2) : 0.0f;   // -dist
        }
        unsigned taken = 0;
        float vals[TOPK_]; int ids[TOPK_];
        for (int j = 0; j < TOPK_; ++j) {
            float best = -3.4e38f; int bi = 0;
            #pragma unroll
            for (int v = 0; v < VT_; ++v) {
                if (!((taken >> v) & 1u) && nd[v] > best) { best = nd[v]; bi = v; }
            }
            vals[j] = best; ids[j] = bi; taken |= (1u << bi);
        }
        float m = vals[0], se = 0.f, e[TOPK_];
        #pragma unroll
        for (int j = 0; j < TOPK_; ++j) { e[j] = expf(vals[j] - m); se += e[j]; }
        float invse = 1.f / se;
        float* row = inc + (size_t)tid * VT_;
        #pragma unroll
        for (int v = 0; v < VT_; ++v) row[v] = 0.f;
        for (int j = 0; j < TOPK_; ++j) row[ids[j]] = e[j] * invse;
    }
    __syncthreads();

    if (tid < K_ * VT_) {
        int k = tid / VT_, v = tid % VT_;
        float cs = 0.f;
        #pragma unroll
        for (int u = 0; u < VT_; ++u) cs += fabsf(inc[(k * VT_ + u) * VT_ + v]);
        float d = wt[tid] / (cs + 1e-8f);
        gv[tid] = wt[tid] * d;
        float s = 0.f;
        const float* row = inc + (size_t)tid * VT_;
        const float* w = wt + k * VT_;
        #pragma unroll
        for (int vv = 0; vv < VT_; ++vv) s += fabsf(row[vv] * w[vv]);
        rs[tid] = s + 1e-8f;
    }
    __syncthreads();

    float ar = alpha[0]; ar = ar > 0.f ? ar : 0.f;
    size_t obase = (size_t)n * K_ * VT_ * 32;
    for (int i = tid; i < K_ * VT_ * VT_; i += 256) {
        int k = i / (VT_ * VT_);
        int r = i % (VT_ * VT_);
        int u = r / VT_, v = r % VT_;
        const float* ru = inc + (k * VT_ + u) * VT_;
        const float* rw = inc + (k * VT_ + v) * VT_;
        const float* g = gv + k * VT_;
        float s = 0.f;
        #pragma unroll
        for (int vv = 0; vv < VT_; ++vv) s += ru[vv] * g[vv] * rw[vv];
        float ha = s / rs[k * VT_ + u];
        float an = edge[i] * adjc[i] / rsA[k * VT_ + u];
        ATg[obase + ((size_t)k * VT_ + v) * 32 + u] = an + ar * ha;  // transposed
    }
    for (int i = tid; i < K_ * VT_ * 2; i += 256) {   // zero pad cols u=30,31
        int k = i / (VT_ * 2), r = i % (VT_ * 2), v = r >> 1, u = 30 + (r & 1);
        ATg[obase + ((size_t)k * VT_ + v) * 32 + u] = 0.f;
    }
}

// ---------------- Kernel 3: register-tiled dense+adj+epilogue ----------------
// Grid: N*K*8 blocks; each block: 8 t (2 slabs of 4). Wave w = t-slice w.
// Lane (og,vh): den tile 4o x 4v from two float4 LDS reads per c.
#define FMA4(A, S) { A.x += w4.x * (S); A.y += w4.y * (S); A.z += w4.z * (S); A.w += w4.w * (S); }
#define YFMA(A, S) { A.x += (S) * a4.x; A.y += (S) * a4.y; A.z += (S) * a4.z; A.w += (S) * a4.w; }
__global__ __launch_bounds__(256) void k_main(
    const float* __restrict__ x, const float* __restrict__ hyper,
    const float* __restrict__ ATg,
    const float* __restrict__ conv_w, const float* __restrict__ conv_b,
    const float* __restrict__ gamma, const float* __restrict__ beta,
    float* __restrict__ out) {
    __shared__ float Wt[CG_ * 32];        // [c][o]
    __shared__ float AT[VT_ * 32];        // [v][u]
    __shared__ float xvs[4 * 32 * 36];    // [tl][c][v], stride 36
    __shared__ float denT[4 * 32 * 36];   // [tl][v][o], stride 36
    __shared__ float scb[32], btb[32], bbb[32];

    int b = blockIdx.x;
    int tchunk = b & 7, k = (b >> 3) & 7, n = b >> 6;
    int tid = threadIdx.x;
    int tl = tid >> 6;                 // wave -> t within slab
    int lane = tid & 63;
    int og = lane >> 3, vh = lane & 7; // 4o x 4v (and 4o x 4u in y phase)

    // Wt transposed (strided global, conflict-free LDS write; conv_w is L2-hot)
    for (int i = tid; i < CG_ * 32; i += 256) {
        int o = i & 31, c = i >> 5;
        Wt[c * 32 + o] = conv_w[(k * OG_ + o) * CG_ + c];
    }
    {   // AT: coalesced float4 copy
        const float4* src = (const float4*)(ATg + (size_t)(n * K_ + k) * VT_ * 32);
        for (int i = tid; i < VT_ * 8; i += 256) ((float4*)AT)[i] = src[i];
    }
    if (tid < 32) {
        scb[tid] = gamma[k * OG_ + tid] * 0.999995000037f;  // 1/sqrt(1+1e-5)
        btb[tid] = beta[k * OG_ + tid];
        bbb[tid] = conv_b[k * OG_ + tid];
    }
    __syncthreads();

    float4 bb4 = *(const float4*)&bbb[4 * og];
    float sc0 = scb[4 * og], sc1 = scb[4 * og + 1], sc2 = scb[4 * og + 2], sc3 = scb[4 * og + 3];
    float bt0 = btb[4 * og], bt1 = btb[4 * og + 1], bt2 = btb[4 * og + 2], bt3 = btb[4 * og + 3];

    for (int ts = 0; ts < 2; ++ts) {
        int tb = tchunk * 8 + ts * 4;
        // stage xv slab [4t][32c][36]
        for (int i = tid; i < 4096; i += 256) {
            int t_l = i >> 10, r = i & 1023, c = r >> 5, v = r & 31;
            float val = 0.f;
            if (v < V_)       val = x[((size_t)(n * C_ + k * CG_ + c) * T_ + tb + t_l) * V_ + v];
            else if (v < VT_) val = hyper[(v - V_) * C_ + k * CG_ + c];
            xvs[(t_l * 32 + c) * 36 + v] = val;
        }
        __syncthreads();

        {   // den phase: acc[vi] = float4 over o
            float4 a0 = bb4, a1 = bb4, a2 = bb4, a3 = bb4;
            const float* xbase = xvs + (tl * 32) * 36 + 4 * vh;
            #pragma unroll 8
            for (int c = 0; c < CG_; ++c) {
                float4 w4 = *(const float4*)&Wt[c * 32 + 4 * og];
                float4 x4 = *(const float4*)&xbase[c * 36];
                FMA4(a0, x4.x) FMA4(a1, x4.y) FMA4(a2, x4.z) FMA4(a3, x4.w)
            }
            float* dp = denT + (tl * 32 + 4 * vh) * 36 + 4 * og;
            *(float4*)&dp[0]      = a0;
            *(float4*)&dp[36]     = a1;
            *(float4*)&dp[72]     = a2;
            *(float4*)&dp[108]    = a3;
        }
        __syncthreads();

        {   // y phase: yacc[oi] = float4 over u
            float4 y0 = {0,0,0,0}, y1 = {0,0,0,0}, y2 = {0,0,0,0}, y3 = {0,0,0,0};
            const float* dbase = denT + (tl * 32) * 36 + 4 * og;
            const float* abase = AT + 4 * vh;
            #pragma unroll 6
            for (int v = 0; v < VT_; ++v) {
                float4 d4 = *(const float4*)&dbase[v * 36];
                float4 a4 = *(const float4*)&abase[v * 32];
                YFMA(y0, d4.x) YFMA(y1, d4.y) YFMA(y2, d4.z) YFMA(y3, d4.w)
            }
            // epilogue: bn scale + beta + residual (xvs row o == residual channel) + relu
            int t = tb + tl;
            size_t base = ((size_t)(n * O_ + k * OG_ + 4 * og) * T_ + t) * V_ + 4 * vh;
            int u0 = 4 * vh;
            #pragma unroll
            for (int oi = 0; oi < 4; ++oi) {
                float4 yy = (oi == 0) ? y0 : (oi == 1) ? y1 : (oi == 2) ? y2 : y3;
                float s = (oi == 0) ? sc0 : (oi == 1) ? sc1 : (oi == 2) ? sc2 : sc3;
                float bt = (oi == 0) ? bt0 : (oi == 1) ? bt1 : (oi == 2) ? bt2 : bt3;
                float4 res = *(const float4*)&xvs[(tl * 32 + 4 * og + oi) * 36 + 4 * vh];
                size_t ob = base + (size_t)oi * T_ * V_;
                float v0 = yy.x * s + bt + res.x; v0 = v0 > 0.f ? v0 : 0.f;
                float v1 = yy.y * s + bt + res.y; v1 = v1 > 0.f ? v1 : 0.f;
                float v2 = yy.z * s + bt + res.z; v2 = v2 > 0.f ? v2 : 0.f;
                float v3 = yy.w * s + bt + res.w; v3 = v3 > 0.f ? v3 : 0.f;
                if (u0 + 0 < V_) out[ob + 0] = v0;
                if (u0 + 1 < V_) out[ob + 1] = v1;
                if (u0 + 2 < V_) out[ob + 2] = v2;
                if (u0 + 3 < V_) out[ob + 3] = v3;
            }
        }
        __syncthreads();
    }
}

extern "C" void kernel_launch(void* const* d_in, const int* in_sizes, int n_in,
                              void* d_out, int out_size, void* d_ws, size_t ws_size,
                              hipStream_t stream) {
    const float* x     = (const float*)d_in[0];
    const float* adjc  = (const float*)d_in[1];
    const float* edge  = (const float*)d_in[2];
    const float* hyper = (const float*)d_in[3];
    const float* alpha = (const float*)d_in[4];
    const float* tvw   = (const float*)d_in[5];
    const float* tvb   = (const float*)d_in[6];
    const float* t1w   = (const float*)d_in[7];
    const float* t1b   = (const float*)d_in[8];
    const float* t2w   = (const float*)d_in[9];
    const float* t2b   = (const float*)d_in[10];
    const float* cw    = (const float*)d_in[11];
    const float* cb    = (const float*)d_in[12];
    const float* gam   = (const float*)d_in[13];
    const float* bet   = (const float*)d_in[14];
    float* out = (float*)d_out;

    float* pooled = (float*)d_ws;                    // N*C*25 fp32
    float* ATg    = pooled + N_ * C_ * V_;           // N*K*30*32 fp32

    k_pool<<<dim3(N_ * 64 + 1), dim3(256), 0, stream>>>(
        x, hyper, pooled, out + (size_t)N_ * O_ * T_ * V_);
    k_graph<<<dim3(N_), dim3(256), 0, stream>>>(
        pooled, hyper, adjc, edge, alpha, tvw, tvb, t1w, t1b, t2w, t2b, ATg);
    k_main<<<dim3(N_ * K_ * 8), dim3(256), 0, stream>>>(
        x, hyper, ATg, cw, cb, gam, bet, out);
}

// Round 4
// 325.174 us; speedup vs baseline: 1.4200x; 1.1963x over previous
//
#include <hip/hip_runtime.h>
#include <hip/hip_bf16.h>

#define N_ 64
#define C_ 256
#define T_ 64
#define V_ 25
#define K_ 8
#define VN_ 5
#define VT_ 30
#define CG_ 32
#define H_ 8
#define O_ 256
#define OG_ 32
#define TOPK_ 9

typedef __attribute__((ext_vector_type(8))) short short8;
typedef __attribute__((ext_vector_type(4))) float f32x4;

__device__ __forceinline__ short bfbits(float f) {
    union { __hip_bfloat16 h; short s; } cv;
    cv.h = __float2bfloat16(f);
    return cv.s;
}
__device__ __forceinline__ short8 mk8(f32x4 a, f32x4 b) {
    short8 r;
    r[0] = bfbits(a[0]); r[1] = bfbits(a[1]); r[2] = bfbits(a[2]); r[3] = bfbits(a[3]);
    r[4] = bfbits(b[0]); r[5] = bfbits(b[1]); r[6] = bfbits(b[2]); r[7] = bfbits(b[3]);
    return r;
}

// ---------------- Kernel 1: coalesced T-mean pooling (+ output-tail copy) ----
__global__ __launch_bounds__(256) void k_pool(const float* __restrict__ x,
                                              const float* __restrict__ hyper,
                                              float* __restrict__ pooled,
                                              float* __restrict__ out_tail) {
    __shared__ float ls[6400];
    int b = blockIdx.x;
    int tid = threadIdx.x;
    if (b >= N_ * 64) {   // tail block: hyper passthrough (VN_*C_ = 1280)
        for (int i = tid; i < VN_ * C_; i += 256) out_tail[i] = hyper[i];
        return;
    }
    int n = b >> 6, c0 = (b & 63) * 4;
    const float4* xp = (const float4*)(x + (size_t)(n * C_ + c0) * (T_ * V_));
    for (int i = tid; i < 1600; i += 256) ((float4*)ls)[i] = xp[i];
    __syncthreads();
    if (tid < 100) {
        int c_l = tid / 25, v = tid % 25;
        const float* p = ls + c_l * 1600 + v;
        float s = 0.f;
        #pragma unroll
        for (int t = 0; t < T_; ++t) s += p[t * 25];
        pooled[(size_t)(n * C_ + c0 + c_l) * 25 + v] = s * (1.0f / T_);
    }
}

// ---------------- Kernel 2: graph construction -> adjR[n][k][u][v] (32x32) ---
__global__ __launch_bounds__(256) void k_graph(
    const float* __restrict__ pooled, const float* __restrict__ hyper,
    const float* __restrict__ adjc, const float* __restrict__ edge,
    const float* __restrict__ alpha,
    const float* __restrict__ to_v_w, const float* __restrict__ to_v_b,
    const float* __restrict__ to_w1_w, const float* __restrict__ to_w1_b,
    const float* __restrict__ to_w2_w, const float* __restrict__ to_w2_b,
    float* __restrict__ adjR) {
    __shared__ float smem[12000];
    float* vproj = smem;              // 1920: [k][v][h]
    float* w1s   = smem + 1920;       // 1920: [q][v], q=k*H+h
    float* pg    = smem + 3840;       // 7680: [c][v]  (phase A only)
    float* inc   = smem + 3840;       // 7200: [k][u][v] (phase B, aliases pg)
    float* wt    = smem + 11040;      // 240
    float* gv    = smem + 11280;      // 240
    float* rs    = smem + 11520;      // 240
    float* rsA   = smem + 11760;      // 240

    int n = blockIdx.x;
    int tid = threadIdx.x;
    for (int i = tid; i < C_ * V_; i += 256) {
        int c = i / V_, v = i % V_;
        pg[c * VT_ + v] = pooled[(size_t)n * C_ * V_ + i];
    }
    for (int i = tid; i < C_ * VN_; i += 256) {
        int c = i / VN_, j = i % VN_;
        pg[c * VT_ + V_ + j] = hyper[j * C_ + c];
    }
    __syncthreads();

    for (int i = tid; i < K_ * VT_ * H_; i += 256) {
        int k = i / (VT_ * H_);
        int r = i % (VT_ * H_);
        int v = r / H_, h = r % H_;
        const float* w = to_v_w + (k * H_ + h) * CG_;
        const float* pgk = pg + (k * CG_) * VT_ + v;
        float s = 0.f;
        #pragma unroll
        for (int c = 0; c < CG_; ++c) s += pgk[c * VT_] * w[c];
        vproj[(k * VT_ + v) * H_ + h] = s + to_v_b[k * H_ + h];
    }
    for (int i = tid; i < K_ * H_ * VT_; i += 256) {
        int k = i / (H_ * VT_);
        int r = i % (H_ * VT_);
        int h = r / VT_, v = r % VT_;
        const float* w = to_w1_w + (k * H_ + h) * CG_;
        const float* pgk = pg + (k * CG_) * VT_ + v;
        float s = 0.f;
        #pragma unroll
        for (int c = 0; c < CG_; ++c) s += pgk[c * VT_] * w[c];
        s += to_w1_b[k * H_ + h];
        w1s[(k * H_ + h) * VT_ + v] = (s > 0.f) ? s : 0.01f * s;  // leaky_relu
    }
    __syncthreads();   // pg dead after this barrier

    if (tid < K_ * VT_) {
        int k = tid / VT_;
        float s = to_w2_b[k];
        #pragma unroll
        for (int q = 0; q < K_ * H_; ++q)
            s += w1s[q * VT_ + (tid % VT_)] * to_w2_w[k * K_ * H_ + q];
        wt[tid] = tanhf(s);
        float sa = 0.f;
        const float* ea = edge + (size_t)tid * VT_;
        const float* aa = adjc + (size_t)tid * VT_;
        #pragma unroll
        for (int w2 = 0; w2 < VT_; ++w2) sa += fabsf(ea[w2] * aa[w2]);
        rsA[tid] = sa + 1e-8f;
    }
    if (tid < K_ * VT_) {
        int k = tid / VT_, u = tid % VT_;
        const float* vu = vproj + (k * VT_ + u) * H_;
        float nd[VT_];
        #pragma unroll
        for (int v = 0; v < VT_; ++v) {
            const float* vv = vproj + (k * VT_ + v) * H_;
            float d2 = 0.f;
            #pragma unroll
            for (int h = 0; h < H_; ++h) { float df = vu[h] - vv[h]; d2 += df * df; }
            nd[v] = (d2 > 0.f) ? -sqrtf(d2) : 0.0f;   // -dist
        }
        unsigned taken = 0;
        float vals[TOPK_]; int ids[TOPK_];
        for (int j = 0; j < TOPK_; ++j) {
            float best = -3.4e38f; int bi = 0;
            #pragma unroll
            for (int v = 0; v < VT_; ++v) {
                if (!((taken >> v) & 1u) && nd[v] > best) { best = nd[v]; bi = v; }
            }
            vals[j] = best; ids[j] = bi; taken |= (1u << bi);
        }
        float m = vals[0], se = 0.f, e[TOPK_];
        #pragma unroll
        for (int j = 0; j < TOPK_; ++j) { e[j] = expf(vals[j] - m); se += e[j]; }
        float invse = 1.f / se;
        float* row = inc + (size_t)tid * VT_;
        #pragma unroll
        for (int v = 0; v < VT_; ++v) row[v] = 0.f;
        for (int j = 0; j < TOPK_; ++j) row[ids[j]] = e[j] * invse;
    }
    __syncthreads();

    if (tid < K_ * VT_) {
        int k = tid / VT_, v = tid % VT_;
        float cs = 0.f;
        #pragma unroll
        for (int u = 0; u < VT_; ++u) cs += fabsf(inc[(k * VT_ + u) * VT_ + v]);
        float d = wt[tid] / (cs + 1e-8f);
        gv[tid] = wt[tid] * d;
        float s = 0.f;
        const float* row = inc + (size_t)tid * VT_;
        const float* w = wt + k * VT_;
        #pragma unroll
        for (int vv = 0; vv < VT_; ++vv) s += fabsf(row[vv] * w[vv]);
        rs[tid] = s + 1e-8f;
    }
    __syncthreads();

    // adjR[u][v] = adj_norm + relu(alpha)*hyper_adj, padded to 32x32 with zeros
    float ar = alpha[0]; ar = ar > 0.f ? ar : 0.f;
    size_t obase = (size_t)n * K_ * 32 * 32;
    for (int i = tid; i < K_ * 32 * 32; i += 256) {
        int k = i >> 10, r = i & 1023, u = r >> 5, v = r & 31;
        float val = 0.f;
        if (u < VT_ && v < VT_) {
            const float* ru = inc + (k * VT_ + u) * VT_;
            const float* rw = inc + (k * VT_ + v) * VT_;
            const float* g = gv + k * VT_;
            float s = 0.f;
            #pragma unroll
            for (int vv = 0; vv < VT_; ++vv) s += ru[vv] * g[vv] * rw[vv];
            float ha = s / rs[k * VT_ + u];
            int ei = (k * VT_ + u) * VT_ + v;
            float an = edge[ei] * adjc[ei] / rsA[k * VT_ + u];
            val = an + ar * ha;
        }
        adjR[obase + i] = val;
    }
}

// ---------------- Kernel 3: MFMA dense+adj+epilogue, 1 wave/block, no barriers
// Block b -> (n, k, tchunk of 8 t). 64 threads = 1 wave.
// GEMM1: Den[o][v] = W[o][c] xv[c][v] + cb  (4x mfma 16x16x32 bf16)
// GEMM2: Y[o][u]   = Den[o][v] A2[u][v]     (4x mfma)
// Epilogue fp32: Y*sc + bt + x + relu.
__global__ __launch_bounds__(64) void k_main(
    const float* __restrict__ x, const float* __restrict__ hyper,
    const float* __restrict__ adjR,
    const float* __restrict__ conv_w, const float* __restrict__ conv_b,
    const float* __restrict__ gamma, const float* __restrict__ beta,
    float* __restrict__ out) {
    __shared__ float xvT[32 * 36];   // [v][c] fp32, stride 36 (16B-aligned rows)
    __shared__ float Den[32 * 36];   // [o][v] fp32, stride 36

    int b = blockIdx.x;
    int tc = b & 7, k = (b >> 3) & 7, n = b >> 6;
    int lane = threadIdx.x;
    int half = lane >> 5;
    int c32 = lane & 31;
    int qd = lane >> 4;        // quad 0..3
    int l16 = lane & 15;

    // --- block-constant register fragments ---
    short8 Wf[2];   // A1[mi]: W[o=16mi+l16][c=qd*8+j]
    #pragma unroll
    for (int mi = 0; mi < 2; ++mi) {
        const float* wp = conv_w + (size_t)(k * OG_ + 16 * mi + l16) * CG_ + qd * 8;
        Wf[mi] = mk8(*(const f32x4*)wp, *(const f32x4*)(wp + 4));
    }
    short8 Bf[2];   // B2[ni]: A2[u=16ni+l16][v=qd*8+j]
    #pragma unroll
    for (int ni = 0; ni < 2; ++ni) {
        const float* ap = adjR + (((size_t)(n * K_ + k)) * 32 + 16 * ni + l16) * 32 + qd * 8;
        Bf[ni] = mk8(*(const f32x4*)ap, *(const f32x4*)(ap + 4));
    }
    f32x4 cb4[2], sc4[2], bt4[2];   // per o-quad: o = 16mi + qd*4 + r
    #pragma unroll
    for (int mi = 0; mi < 2; ++mi) {
        int o0 = k * OG_ + 16 * mi + qd * 4;
        cb4[mi] = *(const f32x4*)(conv_b + o0);
        f32x4 g = *(const f32x4*)(gamma + o0);
        #pragma unroll
        for (int r = 0; r < 4; ++r) g[r] *= 0.999995000037f;  // 1/sqrt(1+1e-5)
        sc4[mi] = g;
        bt4[mi] = *(const f32x4*)(beta + o0);
    }

    // stage hyper rows 25..29 + zero pad rows 30,31 (once; rows 0..24 restaged per t)
    if (lane < 32) {
        #pragma unroll
        for (int j = 0; j < 5; ++j) xvT[(25 + j) * 36 + c32] = hyper[j * C_ + k * CG_ + c32];
        xvT[30 * 36 + c32] = 0.f;
        xvT[31 * 36 + c32] = 0.f;
    }

    const float* xbase = x + ((size_t)(n * C_ + k * CG_) * T_) * V_;
    const size_t orow = (size_t)T_ * V_;

    for (int tl = 0; tl < 8; ++tl) {
        int t = tc * 8 + tl;
        // stage x -> xvT rows 0..24 (transposed [v][c]); lane (c32, half)
        {
            const float* xr = xbase + (size_t)c32 * orow + (size_t)t * V_;
            if (half == 0) {
                #pragma unroll
                for (int i = 0; i < 13; ++i) xvT[i * 36 + c32] = xr[i];
            } else {
                #pragma unroll
                for (int i = 0; i < 12; ++i) xvT[(13 + i) * 36 + c32] = xr[13 + i];
            }
        }

        // GEMM1: C1[mi][ni] += Wf[mi] * Bx[ni]
        short8 Bx[2];
        #pragma unroll
        for (int ni = 0; ni < 2; ++ni) {
            const float* xp = &xvT[(16 * ni + l16) * 36 + qd * 8];
            Bx[ni] = mk8(*(const f32x4*)xp, *(const f32x4*)(xp + 4));
        }
        f32x4 C1[2][2];
        #pragma unroll
        for (int mi = 0; mi < 2; ++mi)
            #pragma unroll
            for (int ni = 0; ni < 2; ++ni) {
                f32x4 z = {0.f, 0.f, 0.f, 0.f};
                C1[mi][ni] = __builtin_amdgcn_mfma_f32_16x16x32_bf16(Wf[mi], Bx[ni], z, 0, 0, 0);
            }

        // Den = C1 + bias  (C/D layout: col v = 16ni+l16, row o = 16mi + qd*4 + r)
        #pragma unroll
        for (int mi = 0; mi < 2; ++mi)
            #pragma unroll
            for (int ni = 0; ni < 2; ++ni) {
                int vcol = 16 * ni + l16;
                #pragma unroll
                for (int r = 0; r < 4; ++r)
                    Den[(16 * mi + qd * 4 + r) * 36 + vcol] = C1[mi][ni][r] + cb4[mi][r];
            }

        // GEMM2: C2[mi][ni] += Af[mi] * Bf[ni]
        short8 Af[2];
        #pragma unroll
        for (int mi = 0; mi < 2; ++mi) {
            const float* dp = &Den[(16 * mi + l16) * 36 + qd * 8];
            Af[mi] = mk8(*(const f32x4*)dp, *(const f32x4*)(dp + 4));
        }
        f32x4 C2[2][2];
        #pragma unroll
        for (int mi = 0; mi < 2; ++mi)
            #pragma unroll
            for (int ni = 0; ni < 2; ++ni) {
                f32x4 z = {0.f, 0.f, 0.f, 0.f};
                C2[mi][ni] = __builtin_amdgcn_mfma_f32_16x16x32_bf16(Af[mi], Bf[ni], z, 0, 0, 0);
            }

        // epilogue: col u = 16ni+l16, rows o = 16mi + qd*4 + r
        #pragma unroll
        for (int mi = 0; mi < 2; ++mi)
            #pragma unroll
            for (int ni = 0; ni < 2; ++ni) {
                int u = 16 * ni + l16;
                f32x4 res = *(const f32x4*)&xvT[u * 36 + 16 * mi + qd * 4];
                if (u < V_) {
                    size_t ob = ((size_t)(n * O_ + k * OG_ + 16 * mi + qd * 4) * T_ + t) * V_ + u;
                    #pragma unroll
                    for (int r = 0; r < 4; ++r) {
                        float val = C2[mi][ni][r] * sc4[mi][r] + bt4[mi][r] + res[r];
                        val = val > 0.f ? val : 0.f;
                        out[ob + (size_t)r * orow] = val;
                    }
                }
            }
    }
}

extern "C" void kernel_launch(void* const* d_in, const int* in_sizes, int n_in,
                              void* d_out, int out_size, void* d_ws, size_t ws_size,
                              hipStream_t stream) {
    const float* x     = (const float*)d_in[0];
    const float* adjc  = (const float*)d_in[1];
    const float* edge  = (const float*)d_in[2];
    const float* hyper = (const float*)d_in[3];
    const float* alpha = (const float*)d_in[4];
    const float* tvw   = (const float*)d_in[5];
    const float* tvb   = (const float*)d_in[6];
    const float* t1w   = (const float*)d_in[7];
    const float* t1b   = (const float*)d_in[8];
    const float* t2w   = (const float*)d_in[9];
    const float* t2b   = (const float*)d_in[10];
    const float* cw    = (const float*)d_in[11];
    const float* cb    = (const float*)d_in[12];
    const float* gam   = (const float*)d_in[13];
    const float* bet   = (const float*)d_in[14];
    float* out = (float*)d_out;

    float* pooled = (float*)d_ws;                    // N*C*25 fp32
    float* adjR   = pooled + N_ * C_ * V_;           // N*K*32*32 fp32

    k_pool<<<dim3(N_ * 64 + 1), dim3(256), 0, stream>>>(
        x, hyper, pooled, out + (size_t)N_ * O_ * T_ * V_);
    k_graph<<<dim3(N_), dim3(256), 0, stream>>>(
        pooled, hyper, adjc, edge, alpha, tvw, tvb, t1w, t1b, t2w, t2b, adjR);
    k_main<<<dim3(N_ * K_ * 8), dim3(64), 0, stream>>>(
        x, hyper, adjR, cw, cb, gam, bet, out);
}